// Round 6
// baseline (983.501 us; speedup 1.0000x reference)
//
#include <hip/hip_runtime.h>
#include <cstddef>

#define DEVINL __device__ __forceinline__

typedef float f32x4 __attribute__((ext_vector_type(4)));
typedef __bf16 bf16x8 __attribute__((ext_vector_type(8)));

DEVINL unsigned short f2bf(float f) {
  union { float f; unsigned int u; } v; v.f = f;
  unsigned int u = v.u;
  unsigned int r = (u + 0x7fffu + ((u >> 16) & 1u)) >> 16;
  return (unsigned short)r;
}
DEVINL float bf2f(unsigned short s) {
  union { unsigned int u; float f; } v; v.u = ((unsigned int)s) << 16;
  return v.f;
}
DEVINL uint4 pack8(const unsigned short o[8]) {
  uint4 r;
  r.x = (unsigned int)o[0] | ((unsigned int)o[1] << 16);
  r.y = (unsigned int)o[2] | ((unsigned int)o[3] << 16);
  r.z = (unsigned int)o[4] | ((unsigned int)o[5] << 16);
  r.w = (unsigned int)o[6] | ((unsigned int)o[7] << 16);
  return r;
}
DEVINL void gload16(const void* g, void* l) {
  __builtin_amdgcn_global_load_lds(
      (__attribute__((address_space(1))) void*)g,
      (__attribute__((address_space(3))) void*)l, 16, 0, 0);
}

// ---------------- fp32 -> bf16 convert ----------------
__global__ __launch_bounds__(256) void k_cvt(const float* __restrict__ in,
                                             unsigned short* __restrict__ out, int n4) {
  int i = blockIdx.x * 256 + threadIdx.x;
  if (i >= n4) return;
  float4 v = ((const float4*)in)[i];
  ushort4 o;
  o.x = f2bf(v.x); o.y = f2bf(v.y); o.z = f2bf(v.z); o.w = f2bf(v.w);
  ((ushort4*)out)[i] = o;
}

// ---------------- GEMM: C[m][n] = sum_k A[m][k] * Bt[n][k] (R2-proven) ------
template <int OUT_BF16>
__global__ __launch_bounds__(256) void k_gemm_bt(const unsigned short* __restrict__ A,
                                                 const unsigned short* __restrict__ Bt,
                                                 void* __restrict__ Cout,
                                                 int M, int N, int K) {
  __shared__ __align__(16) unsigned short As[128 * 32];
  __shared__ __align__(16) unsigned short Bs[128 * 32];
  const int t = threadIdx.x;
  const int lane = t & 63, wv = t >> 6;
  const int wr = wv >> 1, wc = wv & 1;
  const int row0 = blockIdx.y * 128, col0 = blockIdx.x * 128;
  const int fr = lane & 15;
  const int kh = (lane >> 4) * 8;
  f32x4 acc[4][4];
#pragma unroll
  for (int m = 0; m < 4; ++m)
#pragma unroll
    for (int n = 0; n < 4; ++n) acc[m][n] = f32x4{0.f, 0.f, 0.f, 0.f};

  const int off0 = wv * 1024 + lane * 16;
  for (int k0 = 0; k0 < K; k0 += 32) {
#pragma unroll
    for (int it = 0; it < 2; ++it) {
      const int off = off0 + it * 4096;   // byte offset in 8KB tile
      const int r = off >> 6;             // 64 B per row (32 bf16)
      const int cb = off & 63;
      gload16(A + (size_t)(row0 + r) * K + k0 + (cb >> 1),
              (char*)As + wv * 1024 + it * 4096);
      gload16(Bt + (size_t)(col0 + r) * K + k0 + (cb >> 1),
              (char*)Bs + wv * 1024 + it * 4096);
    }
    __syncthreads();
    bf16x8 af[4], bfr[4];
#pragma unroll
    for (int m = 0; m < 4; ++m)
      af[m] = *(const bf16x8*)&As[(wr * 64 + m * 16 + fr) * 32 + kh];
#pragma unroll
    for (int n = 0; n < 4; ++n)
      bfr[n] = *(const bf16x8*)&Bs[(wc * 64 + n * 16 + fr) * 32 + kh];
#pragma unroll
    for (int m = 0; m < 4; ++m)
#pragma unroll
      for (int n = 0; n < 4; ++n)
        acc[m][n] = __builtin_amdgcn_mfma_f32_16x16x32_bf16(af[m], bfr[n], acc[m][n], 0, 0, 0);
    __syncthreads();
  }
  const int rsub = (lane >> 4) * 4;
#pragma unroll
  for (int m = 0; m < 4; ++m)
#pragma unroll
    for (int n = 0; n < 4; ++n)
#pragma unroll
      for (int r = 0; r < 4; ++r) {
        const size_t row = (size_t)row0 + wr * 64 + m * 16 + rsub + r;
        const size_t col = (size_t)col0 + wc * 64 + n * 16 + fr;
        if (OUT_BF16)
          ((unsigned short*)Cout)[row * N + col] = f2bf(acc[m][n][r]);
        else
          ((float*)Cout)[row * N + col] = acc[m][n][r];
      }
}

// ---------------- RoPE + head split (qkv bf16 -> Q/K bf16; V not launched) --
// Compact grid over Q/K slots only: 4096 bt x 640 cols (5 slots x 128) / 8.
__global__ __launch_bounds__(256) void k_rope(const unsigned short* __restrict__ qkv,
                                              const float* __restrict__ fcos,
                                              const float* __restrict__ fsin,
                                              unsigned short* __restrict__ Qb,
                                              unsigned short* __restrict__ Kb) {
  const int idx = blockIdx.x * 256 + threadIdx.x;  // < 4096*640
  if (idx >= 4096 * 640) return;
  const int bt = idx / 640;
  const int r = idx - bt * 640;
  const int g = r / 80;
  const int rr = r - g * 80;
  const int slot = rr >> 4;            // 0..4
  const int d0 = (rr & 15) * 8;
  const int o0 = g * 768 + slot * 128 + d0;
  const int b = bt >> 10, tt = bt & 1023;

  uint4 raw = *(const uint4*)&qkv[(size_t)bt * 6144 + o0];
  unsigned short us[8] = {
      (unsigned short)(raw.x & 0xffff), (unsigned short)(raw.x >> 16),
      (unsigned short)(raw.y & 0xffff), (unsigned short)(raw.y >> 16),
      (unsigned short)(raw.z & 0xffff), (unsigned short)(raw.z >> 16),
      (unsigned short)(raw.w & 0xffff), (unsigned short)(raw.w >> 16)};

  float4 c = *(const float4*)&fcos[tt * 64 + (d0 >> 1)];
  float4 s = *(const float4*)&fsin[tt * 64 + (d0 >> 1)];
  const float sc = (slot < 4) ? 0.08838834764831845f : 1.0f;  // 1/sqrt(128) folded into Q
  float cj[4] = {c.x, c.y, c.z, c.w};
  float sj[4] = {s.x, s.y, s.z, s.w};
  unsigned short os[8];
#pragma unroll
  for (int j = 0; j < 4; ++j) {
    float x0 = bf2f(us[2 * j]), x1 = bf2f(us[2 * j + 1]);
    os[2 * j] = f2bf((x0 * cj[j] - x1 * sj[j]) * sc);
    os[2 * j + 1] = f2bf((x0 * sj[j] + x1 * cj[j]) * sc);
  }
  if (slot < 4) {
    const int h = g * 4 + slot;
    *(uint4*)&Qb[((size_t)(b * 32 + h) * 1024 + tt) * 128 + d0] = pack8(os);
  } else {
    *(uint4*)&Kb[((size_t)(b * 8 + g) * 1024 + tt) * 128 + d0] = pack8(os);
  }
}

// ---------------- V transpose: QKVB -> VT[bg][d=128][t=1024] ----------------
__global__ __launch_bounds__(256) void k_vtrans(const unsigned short* __restrict__ qkv,
                                                unsigned short* __restrict__ VT) {
  const int t = threadIdx.x;
  const int tt0 = blockIdx.x * 128;
  const int bg = blockIdx.y;
  const int b = bg >> 3, g = bg & 7;
  const int tj = t & 15;   // d-block (fast lane index -> coalesced reads)
  const int ti = t >> 4;   // t-block
  union U4 { uint4 v; unsigned int u[4]; };
  U4 in[8], out[8];
  const unsigned short* src =
      qkv + (size_t)(b * 1024 + tt0 + ti * 8) * 6144 + g * 768 + 640 + tj * 8;
#pragma unroll
  for (int r = 0; r < 8; ++r) in[r].v = *(const uint4*)(src + (size_t)r * 6144);
#pragma unroll
  for (int c = 0; c < 8; ++c) {
    const unsigned int sel = (c & 1) ? 0x07060302u : 0x05040100u;
    const int dw = c >> 1;
#pragma unroll
    for (int w = 0; w < 4; ++w)
      out[c].u[w] = __builtin_amdgcn_perm(in[2 * w + 1].u[dw], in[2 * w].u[dw], sel);
  }
  unsigned short* dst = VT + (size_t)bg * 131072 + (size_t)(tj * 8) * 1024 + tt0 + ti * 8;
#pragma unroll
  for (int c = 0; c < 8; ++c) *(uint4*)(dst + (size_t)c * 1024) = out[c].v;
}

// ---------------- causal GQA flash attention, barrier-free, K/V direct from L2
// block = (q-tile 64, (b,h)); 4 independent waves x 16 q-rows; KV tiles of 64.
// K/V per (b,g) = 256 KB each -> L1/L2-resident; no LDS staging, no barriers.
__global__ __launch_bounds__(256) void k_attn(const unsigned short* __restrict__ Qb,
                                              const unsigned short* __restrict__ Kb,
                                              const unsigned short* __restrict__ VT,
                                              unsigned short* __restrict__ AO) {
  __shared__ __align__(16) unsigned short Ps[4 * 16 * 64];  // per-wave [q16][kv64], XOR-swz
  const int t = threadIdx.x, lane = t & 63, wv = t >> 6;
  const int bh = blockIdx.y;
  const int b = bh >> 5, h = bh & 31, g = h >> 2;
  const int qi = 15 - blockIdx.x;   // longest-first dispatch
  const int q0 = qi * 64;
  const int fr = lane & 15, kq = lane >> 4;
  const unsigned short* Kp = Kb + (size_t)(b * 8 + g) * (1024 * 128);  // [t][d]
  const unsigned short* Vp = VT + (size_t)(b * 8 + g) * (128 * 1024);  // [d][t]

  bf16x8 qf[4];
  {
    const unsigned short* Qp = Qb + ((size_t)(b * 32 + h) * 1024 + q0 + wv * 16 + fr) * 128;
#pragma unroll
    for (int ks = 0; ks < 4; ++ks) qf[ks] = *(const bf16x8*)&Qp[ks * 32 + kq * 8];
  }
  float mrow[4] = {-1e30f, -1e30f, -1e30f, -1e30f};
  float lrow[4] = {0.f, 0.f, 0.f, 0.f};
  f32x4 of[8];
#pragma unroll
  for (int n = 0; n < 8; ++n) of[n] = f32x4{0.f, 0.f, 0.f, 0.f};

  for (int kt = 0; kt <= qi; ++kt) {
    const int kv0 = kt * 64;

    // S = Q K^T : 16q x 64kv per wave; K fragments direct from global (L1/L2)
    f32x4 sacc[4];
#pragma unroll
    for (int n = 0; n < 4; ++n) sacc[n] = f32x4{0.f, 0.f, 0.f, 0.f};
#pragma unroll
    for (int n = 0; n < 4; ++n) {
      const unsigned short* kr = Kp + (size_t)(kv0 + n * 16 + fr) * 128 + kq * 8;
      bf16x8 kf0 = *(const bf16x8*)(kr);
      bf16x8 kf1 = *(const bf16x8*)(kr + 32);
      bf16x8 kf2 = *(const bf16x8*)(kr + 64);
      bf16x8 kf3 = *(const bf16x8*)(kr + 96);
      sacc[n] = __builtin_amdgcn_mfma_f32_16x16x32_bf16(qf[0], kf0, sacc[n], 0, 0, 0);
      sacc[n] = __builtin_amdgcn_mfma_f32_16x16x32_bf16(qf[1], kf1, sacc[n], 0, 0, 0);
      sacc[n] = __builtin_amdgcn_mfma_f32_16x16x32_bf16(qf[2], kf2, sacc[n], 0, 0, 0);
      sacc[n] = __builtin_amdgcn_mfma_f32_16x16x32_bf16(qf[3], kf3, sacc[n], 0, 0, 0);
    }

    // online softmax; rows: q = kq*4+rg, cols: kv = n*16+fr
#pragma unroll
    for (int rg = 0; rg < 4; ++rg) {
      const int qrow = q0 + wv * 16 + kq * 4 + rg;
      float s[4];
#pragma unroll
      for (int n = 0; n < 4; ++n) {
        s[n] = sacc[n][rg];
        if (kv0 + n * 16 + fr > qrow) s[n] = -1e30f;
      }
      float mx = fmaxf(fmaxf(s[0], s[1]), fmaxf(s[2], s[3]));
#pragma unroll
      for (int o = 1; o < 16; o <<= 1) mx = fmaxf(mx, __shfl_xor(mx, o));
      const float mnew = fmaxf(mrow[rg], mx);
      float p[4];
#pragma unroll
      for (int n = 0; n < 4; ++n) p[n] = __expf(s[n] - mnew);
      float sum = (p[0] + p[1]) + (p[2] + p[3]);
#pragma unroll
      for (int o = 1; o < 16; o <<= 1) sum += __shfl_xor(sum, o);
      const float fac = __expf(mrow[rg] - mnew);
      lrow[rg] = lrow[rg] * fac + sum;
      mrow[rg] = mnew;
#pragma unroll
      for (int n = 0; n < 8; ++n) of[n][rg] *= fac;
      const int q = kq * 4 + rg;
      const int swp = (q & 7) << 4;
#pragma unroll
      for (int n = 0; n < 4; ++n)
        *(unsigned short*)((char*)Ps + wv * 2048 + q * 128 + ((2 * (n * 16 + fr)) ^ swp)) =
            f2bf(p[n]);
    }
    asm volatile("s_waitcnt lgkmcnt(0)" ::: "memory");
    __builtin_amdgcn_sched_barrier(0);

    // PV: O += P[16x64] * V^T; V fragments direct from global (L1/L2)
    bf16x8 pa[2];
#pragma unroll
    for (int kk = 0; kk < 2; ++kk)
      pa[kk] = *(const bf16x8*)((const char*)Ps + wv * 2048 + fr * 128 +
                                ((kk * 64 + kq * 16) ^ ((fr & 7) << 4)));
#pragma unroll
    for (int n = 0; n < 8; ++n) {
      const unsigned short* vr = Vp + (size_t)(n * 16 + fr) * 1024 + kv0 + kq * 8;
      bf16x8 vf0 = *(const bf16x8*)(vr);
      bf16x8 vf1 = *(const bf16x8*)(vr + 32);
      of[n] = __builtin_amdgcn_mfma_f32_16x16x32_bf16(pa[0], vf0, of[n], 0, 0, 0);
      of[n] = __builtin_amdgcn_mfma_f32_16x16x32_bf16(pa[1], vf1, of[n], 0, 0, 0);
    }
  }

  float inv[4];
#pragma unroll
  for (int rg = 0; rg < 4; ++rg) inv[rg] = 1.0f / lrow[rg];
#pragma unroll
  for (int n = 0; n < 8; ++n)
#pragma unroll
    for (int rg = 0; rg < 4; ++rg) {
      const size_t row = (size_t)b * 1024 + q0 + wv * 16 + kq * 4 + rg;
      const size_t col = (size_t)h * 128 + n * 16 + fr;
      AO[row * 4096 + col] = f2bf(of[n][rg] * inv[rg]);
    }
}

// ---------------- launch ----------------
extern "C" void kernel_launch(void* const* d_in, const int* in_sizes, int n_in,
                              void* d_out, int out_size, void* d_ws, size_t ws_size,
                              hipStream_t stream) {
  const float* x = (const float*)d_in[0];
  const float* w_qkv = (const float*)d_in[1];
  const float* w_proj = (const float*)d_in[2];
  const float* fcos = (const float*)d_in[3];
  const float* fsin = (const float*)d_in[4];
  float* out = (float*)d_out;

  char* ws = (char*)d_ws;
  unsigned short* XB    = (unsigned short*)(ws + 0);          // x bf16
  unsigned short* WQKVB = (unsigned short*)(ws + 33554432);   // w_qkv bf16
  unsigned short* QKVB  = (unsigned short*)(ws + 83886080);   // qkv bf16
  unsigned short* QB    = (unsigned short*)(ws + 134217728);
  unsigned short* KB    = (unsigned short*)(ws + 167772160);
  unsigned short* VTB   = (unsigned short*)(ws + 176160768);  // V^T [bg][128][1024]
  unsigned short* WPROJB = XB;    // reuse x slot after GEMM1
  unsigned short* AOB    = QKVB;  // reuse qkv slot (V read via VTB)

  k_cvt<<<16384, 256, 0, stream>>>(x, XB, 4194304);
  k_cvt<<<24576, 256, 0, stream>>>(w_qkv, WQKVB, 6291456);
  k_gemm_bt<1><<<dim3(48, 32), 256, 0, stream>>>(XB, WQKVB, QKVB, 4096, 6144, 4096);
  k_cvt<<<16384, 256, 0, stream>>>(w_proj, WPROJB, 4194304);
  k_rope<<<10240, 256, 0, stream>>>(QKVB, fcos, fsin, QB, KB);
  k_vtrans<<<dim3(8, 32), 256, 0, stream>>>(QKVB, VTB);
  k_attn<<<dim3(16, 128), 256, 0, stream>>>(QB, KB, VTB, AOB);
  k_gemm_bt<0><<<dim3(32, 32), 256, 0, stream>>>(AOB, WPROJB, out, 4096, 4096, 4096);
}

// Round 7
// 596.351 us; speedup vs baseline: 1.6492x; 1.6492x over previous
//
#include <hip/hip_runtime.h>
#include <cstddef>

#define DEVINL __device__ __forceinline__

typedef float f32x4 __attribute__((ext_vector_type(4)));
typedef __bf16 bf16x8 __attribute__((ext_vector_type(8)));

DEVINL unsigned short f2bf(float f) {
  union { float f; unsigned int u; } v; v.f = f;
  unsigned int u = v.u;
  unsigned int r = (u + 0x7fffu + ((u >> 16) & 1u)) >> 16;
  return (unsigned short)r;
}
DEVINL float bf2f(unsigned short s) {
  union { unsigned int u; float f; } v; v.u = ((unsigned int)s) << 16;
  return v.f;
}
DEVINL uint4 pack8(const unsigned short o[8]) {
  uint4 r;
  r.x = (unsigned int)o[0] | ((unsigned int)o[1] << 16);
  r.y = (unsigned int)o[2] | ((unsigned int)o[3] << 16);
  r.z = (unsigned int)o[4] | ((unsigned int)o[5] << 16);
  r.w = (unsigned int)o[6] | ((unsigned int)o[7] << 16);
  return r;
}
DEVINL void gload16(const void* g, void* l) {
  __builtin_amdgcn_global_load_lds(
      (__attribute__((address_space(1))) void*)g,
      (__attribute__((address_space(3))) void*)l, 16, 0, 0);
}

// ---------------- fp32 -> bf16 convert ----------------
__global__ __launch_bounds__(256) void k_cvt(const float* __restrict__ in,
                                             unsigned short* __restrict__ out, int n4) {
  int i = blockIdx.x * 256 + threadIdx.x;
  if (i >= n4) return;
  float4 v = ((const float4*)in)[i];
  ushort4 o;
  o.x = f2bf(v.x); o.y = f2bf(v.y); o.z = f2bf(v.z); o.w = f2bf(v.w);
  ((ushort4*)out)[i] = o;
}

// ---------------- GEMM 256x256, BK=64, 8-phase pipeline (m201-faithful) -----
// C[m][n] = sum_k A[m][k]*Bt[n][k]. 512 thr = 8 waves (2M x 4N).
// LDS [2 dbuf][2 ks][256 rows][64B]; granule-rotation swizzle (verified 0-confl).
// Per K-tile: 4 phases {ds_read frags; stage 1 unit (2 gload16); barrier;
// lgkm0; 16 MFMA; barrier}. One vmcnt(2) per tile at phase 3 guarding the
// NEXT tile's units (first read 2 barriers later) - never vmcnt(0) mid-loop.
template <int OUT_BF16>
__global__ __launch_bounds__(512, 1) void k_gemm256(const unsigned short* __restrict__ A,
                                                    const unsigned short* __restrict__ Bt,
                                                    void* __restrict__ Cout,
                                                    int M, int N, int K) {
  __shared__ __align__(16) unsigned short As[2][2][256 * 32];
  __shared__ __align__(16) unsigned short Bs[2][2][256 * 32];
  const int t = threadIdx.x, lane = t & 63;
  const int wid = t >> 6, wm = wid >> 2, wn = wid & 3;
  const int fr = lane & 15, kq = lane >> 4;
  const int nwg = gridDim.x * gridDim.y;   // % 8 == 0 at both call sites
  int lin = blockIdx.y * gridDim.x + blockIdx.x;
  lin = (lin & 7) * (nwg >> 3) + (lin >> 3);
  const int bx = lin % gridDim.x, by = lin / gridDim.x;
  const int row0 = by * 256, col0 = bx * 256;
  const int NT = K >> 6;

  // stage-unit addressing: thread t covers LDS bytes (i*512+t)*16 of a 16KB unit
  int srow[2], sgs[2];
#pragma unroll
  for (int i = 0; i < 2; ++i) {
    const int off = (i * 512 + t) * 16;
    srow[i] = off >> 6;                       // 64B per row
    sgs[i] = (((off >> 4) & 3) - (srow[i] >> 1)) & 3;  // global granule for slot
  }

#define STAGE_A(KT, KS)                                                        \
  do {                                                                         \
    const int b_ = (KT) & 1;                                                   \
    _Pragma("unroll") for (int i = 0; i < 2; ++i)                              \
        gload16(A + (size_t)(row0 + srow[i]) * K + (KT) * 64 + (KS) * 32 +     \
                    sgs[i] * 8,                                                \
                (char*)&As[b_][KS][0] + i * 8192 + wid * 1024);                \
  } while (0)
#define STAGE_B(KT, KS)                                                        \
  do {                                                                         \
    const int b_ = (KT) & 1;                                                   \
    _Pragma("unroll") for (int i = 0; i < 2; ++i)                              \
        gload16(Bt + (size_t)(col0 + srow[i]) * K + (KT) * 64 + (KS) * 32 +    \
                    sgs[i] * 8,                                                \
                (char*)&Bs[b_][KS][0] + i * 8192 + wid * 1024);                \
  } while (0)
#define LDFRAG(BUFP, ROW) \
  (*(const bf16x8*)((const char*)(BUFP) + (ROW) * 64 + ((((ROW) >> 1) + kq & 3) << 4)))

  f32x4 acc[8][4];
#pragma unroll
  for (int m = 0; m < 8; ++m)
#pragma unroll
    for (int n = 0; n < 4; ++n) acc[m][n] = f32x4{0.f, 0.f, 0.f, 0.f};

  // prologue: U(0,0..3), U(1,0), U(1,1); wait U(0,*) (2 units newer in flight)
  STAGE_A(0, 0); STAGE_B(0, 0); STAGE_A(0, 1); STAGE_B(0, 1);
  STAGE_A(1, 0); STAGE_B(1, 0);
  asm volatile("s_waitcnt vmcnt(4)" ::: "memory");
  __builtin_amdgcn_s_barrier();

  for (int kt = 0; kt < NT; ++kt) {
    const unsigned short* As0 = &As[kt & 1][0][0];
    const unsigned short* As1 = &As[kt & 1][1][0];
    const unsigned short* Bs0 = &Bs[kt & 1][0][0];
    const unsigned short* Bs1 = &Bs[kt & 1][1][0];
    bf16x8 a0[4], a1[4], b0[4], b1[4];

    // ---- phase 0: ks0/mh0 ----
#pragma unroll
    for (int m = 0; m < 4; ++m) a0[m] = LDFRAG(As0, wm * 128 + m * 16 + fr);
#pragma unroll
    for (int n = 0; n < 4; ++n) b0[n] = LDFRAG(Bs0, wn * 64 + n * 16 + fr);
    if (kt + 1 < NT) STAGE_A(kt + 1, 1);
    __builtin_amdgcn_sched_barrier(0);
    __builtin_amdgcn_s_barrier();
    asm volatile("s_waitcnt lgkmcnt(0)" ::: "memory");
    __builtin_amdgcn_sched_barrier(0);
    __builtin_amdgcn_s_setprio(1);
#pragma unroll
    for (int m = 0; m < 4; ++m)
#pragma unroll
      for (int n = 0; n < 4; ++n)
        acc[m][n] = __builtin_amdgcn_mfma_f32_16x16x32_bf16(a0[m], b0[n], acc[m][n], 0, 0, 0);
    __builtin_amdgcn_s_setprio(0);
    __builtin_amdgcn_s_barrier();

    // ---- phase 1: ks0/mh1 ----
#pragma unroll
    for (int m = 0; m < 4; ++m) a1[m] = LDFRAG(As0, wm * 128 + 64 + m * 16 + fr);
    if (kt + 1 < NT) STAGE_B(kt + 1, 1);
    __builtin_amdgcn_sched_barrier(0);
    __builtin_amdgcn_s_barrier();
    asm volatile("s_waitcnt lgkmcnt(0)" ::: "memory");
    __builtin_amdgcn_sched_barrier(0);
    __builtin_amdgcn_s_setprio(1);
#pragma unroll
    for (int m = 0; m < 4; ++m)
#pragma unroll
      for (int n = 0; n < 4; ++n)
        acc[m + 4][n] = __builtin_amdgcn_mfma_f32_16x16x32_bf16(a1[m], b0[n], acc[m + 4][n], 0, 0, 0);
    __builtin_amdgcn_s_setprio(0);
    __builtin_amdgcn_s_barrier();

    // ---- phase 2: ks1/mh0 ----
#pragma unroll
    for (int m = 0; m < 4; ++m) a0[m] = LDFRAG(As1, wm * 128 + m * 16 + fr);
#pragma unroll
    for (int n = 0; n < 4; ++n) b1[n] = LDFRAG(Bs1, wn * 64 + n * 16 + fr);
    if (kt + 2 < NT) STAGE_A(kt + 2, 0);
    __builtin_amdgcn_sched_barrier(0);
    __builtin_amdgcn_s_barrier();
    asm volatile("s_waitcnt lgkmcnt(0)" ::: "memory");
    __builtin_amdgcn_sched_barrier(0);
    __builtin_amdgcn_s_setprio(1);
#pragma unroll
    for (int m = 0; m < 4; ++m)
#pragma unroll
      for (int n = 0; n < 4; ++n)
        acc[m][n] = __builtin_amdgcn_mfma_f32_16x16x32_bf16(a0[m], b1[n], acc[m][n], 0, 0, 0);
    __builtin_amdgcn_s_setprio(0);
    __builtin_amdgcn_s_barrier();

    // ---- phase 3: ks1/mh1 + next-tile vmcnt guard ----
#pragma unroll
    for (int m = 0; m < 4; ++m) a1[m] = LDFRAG(As1, wm * 128 + 64 + m * 16 + fr);
    if (kt + 1 < NT) {
      if (kt + 2 < NT) asm volatile("s_waitcnt vmcnt(2)" ::: "memory");
      else             asm volatile("s_waitcnt vmcnt(0)" ::: "memory");
    }
    if (kt + 2 < NT) STAGE_B(kt + 2, 0);
    __builtin_amdgcn_sched_barrier(0);
    __builtin_amdgcn_s_barrier();
    asm volatile("s_waitcnt lgkmcnt(0)" ::: "memory");
    __builtin_amdgcn_sched_barrier(0);
    __builtin_amdgcn_s_setprio(1);
#pragma unroll
    for (int m = 0; m < 4; ++m)
#pragma unroll
      for (int n = 0; n < 4; ++n)
        acc[m + 4][n] = __builtin_amdgcn_mfma_f32_16x16x32_bf16(a1[m], b1[n], acc[m + 4][n], 0, 0, 0);
    __builtin_amdgcn_s_setprio(0);
    __builtin_amdgcn_s_barrier();
  }
#undef STAGE_A
#undef STAGE_B
#undef LDFRAG

  const int rsub = kq * 4;
#pragma unroll
  for (int m = 0; m < 8; ++m)
#pragma unroll
    for (int n = 0; n < 4; ++n)
#pragma unroll
      for (int r = 0; r < 4; ++r) {
        const size_t row = (size_t)row0 + wm * 128 + m * 16 + rsub + r;
        const size_t col = (size_t)col0 + wn * 64 + n * 16 + fr;
        if (OUT_BF16)
          ((unsigned short*)Cout)[row * N + col] = f2bf(acc[m][n][r]);
        else
          ((float*)Cout)[row * N + col] = acc[m][n][r];
      }
}

// ---------------- RoPE + head split (qkv bf16 -> Q/K bf16; V not launched) --
__global__ __launch_bounds__(256) void k_rope(const unsigned short* __restrict__ qkv,
                                              const float* __restrict__ fcos,
                                              const float* __restrict__ fsin,
                                              unsigned short* __restrict__ Qb,
                                              unsigned short* __restrict__ Kb) {
  const int idx = blockIdx.x * 256 + threadIdx.x;  // < 4096*640
  if (idx >= 4096 * 640) return;
  const int bt = idx / 640;
  const int r = idx - bt * 640;
  const int g = r / 80;
  const int rr = r - g * 80;
  const int slot = rr >> 4;            // 0..4
  const int d0 = (rr & 15) * 8;
  const int o0 = g * 768 + slot * 128 + d0;
  const int b = bt >> 10, tt = bt & 1023;

  uint4 raw = *(const uint4*)&qkv[(size_t)bt * 6144 + o0];
  unsigned short us[8] = {
      (unsigned short)(raw.x & 0xffff), (unsigned short)(raw.x >> 16),
      (unsigned short)(raw.y & 0xffff), (unsigned short)(raw.y >> 16),
      (unsigned short)(raw.z & 0xffff), (unsigned short)(raw.z >> 16),
      (unsigned short)(raw.w & 0xffff), (unsigned short)(raw.w >> 16)};

  float4 c = *(const float4*)&fcos[tt * 64 + (d0 >> 1)];
  float4 s = *(const float4*)&fsin[tt * 64 + (d0 >> 1)];
  const float sc = (slot < 4) ? 0.08838834764831845f : 1.0f;  // 1/sqrt(128) into Q
  float cj[4] = {c.x, c.y, c.z, c.w};
  float sj[4] = {s.x, s.y, s.z, s.w};
  unsigned short os[8];
#pragma unroll
  for (int j = 0; j < 4; ++j) {
    float x0 = bf2f(us[2 * j]), x1 = bf2f(us[2 * j + 1]);
    os[2 * j] = f2bf((x0 * cj[j] - x1 * sj[j]) * sc);
    os[2 * j + 1] = f2bf((x0 * sj[j] + x1 * cj[j]) * sc);
  }
  if (slot < 4) {
    const int h = g * 4 + slot;
    *(uint4*)&Qb[((size_t)(b * 32 + h) * 1024 + tt) * 128 + d0] = pack8(os);
  } else {
    *(uint4*)&Kb[((size_t)(b * 8 + g) * 1024 + tt) * 128 + d0] = pack8(os);
  }
}

// ---------------- V transpose: QKVB -> VT[bg][d=128][t=1024] ----------------
__global__ __launch_bounds__(256) void k_vtrans(const unsigned short* __restrict__ qkv,
                                                unsigned short* __restrict__ VT) {
  const int t = threadIdx.x;
  const int tt0 = blockIdx.x * 128;
  const int bg = blockIdx.y;
  const int b = bg >> 3, g = bg & 7;
  const int tj = t & 15;
  const int ti = t >> 4;
  union U4 { uint4 v; unsigned int u[4]; };
  U4 in[8], out[8];
  const unsigned short* src =
      qkv + (size_t)(b * 1024 + tt0 + ti * 8) * 6144 + g * 768 + 640 + tj * 8;
#pragma unroll
  for (int r = 0; r < 8; ++r) in[r].v = *(const uint4*)(src + (size_t)r * 6144);
#pragma unroll
  for (int c = 0; c < 8; ++c) {
    const unsigned int sel = (c & 1) ? 0x07060302u : 0x05040100u;
    const int dw = c >> 1;
#pragma unroll
    for (int w = 0; w < 4; ++w)
      out[c].u[w] = __builtin_amdgcn_perm(in[2 * w + 1].u[dw], in[2 * w].u[dw], sel);
  }
  unsigned short* dst = VT + (size_t)bg * 131072 + (size_t)(tj * 8) * 1024 + tt0 + ti * 8;
#pragma unroll
  for (int c = 0; c < 8; ++c) *(uint4*)(dst + (size_t)c * 1024) = out[c].v;
}

// ---------------- causal GQA flash attention (R2-proven structure) ----------
__global__ __launch_bounds__(256) void k_attn(const unsigned short* __restrict__ Qb,
                                              const unsigned short* __restrict__ Kb,
                                              const unsigned short* __restrict__ VT,
                                              unsigned short* __restrict__ AO) {
  __shared__ __align__(16) unsigned short Ks[64 * 128];   // [kv][d], 256B rows, XOR-swz
  __shared__ __align__(16) unsigned short Vt[128 * 64];   // [d][kv], 128B rows, XOR-swz
  __shared__ __align__(16) unsigned short Ps[4 * 16 * 64]; // per-wave [q16][kv64], XOR-swz
  const int t = threadIdx.x, lane = t & 63, wv = t >> 6;
  const int bh = blockIdx.y;
  const int b = bh >> 5, h = bh & 31, g = h >> 2;
  const int qi = 15 - blockIdx.x;   // longest-first
  const int q0 = qi * 64;
  const int fr = lane & 15, kq = lane >> 4;
  const size_t kvbase = (size_t)(b * 8 + g) * (1024 * 128);
  const size_t vtbase = (size_t)(b * 8 + g) * (128 * 1024);

  bf16x8 qf[4];
  {
    const unsigned short* Qp = Qb + ((size_t)(b * 32 + h) * 1024 + q0 + wv * 16 + fr) * 128;
#pragma unroll
    for (int ks = 0; ks < 4; ++ks) qf[ks] = *(const bf16x8*)&Qp[ks * 32 + kq * 8];
  }
  float mrow[4] = {-1e30f, -1e30f, -1e30f, -1e30f};
  float lrow[4] = {0.f, 0.f, 0.f, 0.f};
  f32x4 of[8];
#pragma unroll
  for (int n = 0; n < 8; ++n) of[n] = f32x4{0.f, 0.f, 0.f, 0.f};

  for (int kt = 0; kt <= qi; ++kt) {
    const int kv0 = kt * 64;
#pragma unroll
    for (int it = 0; it < 4; ++it) {
      const int off = it * 4096 + wv * 1024 + lane * 16;
      {
        const int r = off >> 8, cb = off & 255;
        const int scb = cb ^ ((r & 7) << 4);
        gload16(Kb + kvbase + (size_t)(kv0 + r) * 128 + (scb >> 1),
                (char*)Ks + it * 4096 + wv * 1024);
      }
      {
        const int rd = off >> 7, cb = off & 127;
        const int scb = cb ^ ((rd & 7) << 4);
        gload16(VT + vtbase + (size_t)rd * 1024 + kv0 + (scb >> 1),
                (char*)Vt + it * 4096 + wv * 1024);
      }
    }
    __syncthreads();

    f32x4 sacc[4];
#pragma unroll
    for (int n = 0; n < 4; ++n) sacc[n] = f32x4{0.f, 0.f, 0.f, 0.f};
#pragma unroll
    for (int n = 0; n < 4; ++n) {
      const int row = n * 16 + fr;
      const int sw = (row & 7) << 4;
#pragma unroll
      for (int ks = 0; ks < 4; ++ks) {
        bf16x8 kf = *(const bf16x8*)((const char*)Ks + row * 256 + ((ks * 64 + kq * 16) ^ sw));
        sacc[n] = __builtin_amdgcn_mfma_f32_16x16x32_bf16(qf[ks], kf, sacc[n], 0, 0, 0);
      }
    }

#pragma unroll
    for (int rg = 0; rg < 4; ++rg) {
      const int qrow = q0 + wv * 16 + kq * 4 + rg;
      float s[4];
#pragma unroll
      for (int n = 0; n < 4; ++n) {
        s[n] = sacc[n][rg];
        if (kv0 + n * 16 + fr > qrow) s[n] = -1e30f;
      }
      float mx = fmaxf(fmaxf(s[0], s[1]), fmaxf(s[2], s[3]));
#pragma unroll
      for (int o = 1; o < 16; o <<= 1) mx = fmaxf(mx, __shfl_xor(mx, o));
      const float mnew = fmaxf(mrow[rg], mx);
      float p[4];
#pragma unroll
      for (int n = 0; n < 4; ++n) p[n] = __expf(s[n] - mnew);
      float sum = (p[0] + p[1]) + (p[2] + p[3]);
#pragma unroll
      for (int o = 1; o < 16; o <<= 1) sum += __shfl_xor(sum, o);
      const float fac = __expf(mrow[rg] - mnew);
      lrow[rg] = lrow[rg] * fac + sum;
      mrow[rg] = mnew;
#pragma unroll
      for (int n = 0; n < 8; ++n) of[n][rg] *= fac;
      const int q = kq * 4 + rg;
      const int swp = (q & 7) << 4;
#pragma unroll
      for (int n = 0; n < 4; ++n)
        *(unsigned short*)((char*)Ps + wv * 2048 + q * 128 + ((2 * (n * 16 + fr)) ^ swp)) =
            f2bf(p[n]);
    }
    asm volatile("s_waitcnt lgkmcnt(0)" ::: "memory");
    __builtin_amdgcn_sched_barrier(0);

    bf16x8 pa[2];
#pragma unroll
    for (int kk = 0; kk < 2; ++kk)
      pa[kk] = *(const bf16x8*)((const char*)Ps + wv * 2048 + fr * 128 +
                                ((kk * 64 + kq * 16) ^ ((fr & 7) << 4)));
#pragma unroll
    for (int n = 0; n < 8; ++n) {
      const int row = n * 16 + fr;
      const int sw = (row & 7) << 4;
#pragma unroll
      for (int kk = 0; kk < 2; ++kk) {
        bf16x8 vf = *(const bf16x8*)((const char*)Vt + row * 128 + ((kk * 64 + kq * 16) ^ sw));
        of[n] = __builtin_amdgcn_mfma_f32_16x16x32_bf16(pa[kk], vf, of[n], 0, 0, 0);
      }
    }
    __syncthreads();
  }

  float inv[4];
#pragma unroll
  for (int rg = 0; rg < 4; ++rg) inv[rg] = 1.0f / lrow[rg];
#pragma unroll
  for (int n = 0; n < 8; ++n)
#pragma unroll
    for (int rg = 0; rg < 4; ++rg) {
      const size_t row = (size_t)b * 1024 + q0 + wv * 16 + kq * 4 + rg;
      const size_t col = (size_t)h * 128 + n * 16 + fr;
      AO[row * 4096 + col] = f2bf(of[n][rg] * inv[rg]);
    }
}

// ---------------- launch ----------------
extern "C" void kernel_launch(void* const* d_in, const int* in_sizes, int n_in,
                              void* d_out, int out_size, void* d_ws, size_t ws_size,
                              hipStream_t stream) {
  const float* x = (const float*)d_in[0];
  const float* w_qkv = (const float*)d_in[1];
  const float* w_proj = (const float*)d_in[2];
  const float* fcos = (const float*)d_in[3];
  const float* fsin = (const float*)d_in[4];
  float* out = (float*)d_out;

  char* ws = (char*)d_ws;
  unsigned short* XB    = (unsigned short*)(ws + 0);
  unsigned short* WQKVB = (unsigned short*)(ws + 33554432);
  unsigned short* QKVB  = (unsigned short*)(ws + 83886080);
  unsigned short* QB    = (unsigned short*)(ws + 134217728);
  unsigned short* KB    = (unsigned short*)(ws + 167772160);
  unsigned short* VTB   = (unsigned short*)(ws + 176160768);
  unsigned short* WPROJB = XB;
  unsigned short* AOB    = QKVB;

  k_cvt<<<16384, 256, 0, stream>>>(x, XB, 4194304);
  k_cvt<<<24576, 256, 0, stream>>>(w_qkv, WQKVB, 6291456);
  k_gemm256<1><<<dim3(24, 16), 512, 0, stream>>>(XB, WQKVB, QKVB, 4096, 6144, 4096);
  k_cvt<<<16384, 256, 0, stream>>>(w_proj, WPROJB, 4194304);
  k_rope<<<10240, 256, 0, stream>>>(QKVB, fcos, fsin, QB, KB);
  k_vtrans<<<dim3(8, 32), 256, 0, stream>>>(QKVB, VTB);
  k_attn<<<dim3(16, 128), 256, 0, stream>>>(QB, KB, VTB, AOB);
  k_gemm256<0><<<dim3(16, 16), 512, 0, stream>>>(AOB, WPROJB, out, 4096, 4096, 4096);
}

// Round 8
// 512.269 us; speedup vs baseline: 1.9199x; 1.1641x over previous
//
#include <hip/hip_runtime.h>
#include <cstddef>

#define DEVINL __device__ __forceinline__

typedef float f32x4 __attribute__((ext_vector_type(4)));
typedef __bf16 bf16x8 __attribute__((ext_vector_type(8)));

DEVINL unsigned short f2bf(float f) {
  union { float f; unsigned int u; } v; v.f = f;
  unsigned int u = v.u;
  unsigned int r = (u + 0x7fffu + ((u >> 16) & 1u)) >> 16;
  return (unsigned short)r;
}
DEVINL float bf2f(unsigned short s) {
  union { unsigned int u; float f; } v; v.u = ((unsigned int)s) << 16;
  return v.f;
}
DEVINL uint4 pack8(const unsigned short o[8]) {
  uint4 r;
  r.x = (unsigned int)o[0] | ((unsigned int)o[1] << 16);
  r.y = (unsigned int)o[2] | ((unsigned int)o[3] << 16);
  r.z = (unsigned int)o[4] | ((unsigned int)o[5] << 16);
  r.w = (unsigned int)o[6] | ((unsigned int)o[7] << 16);
  return r;
}
DEVINL void gload16(const void* g, void* l) {
  __builtin_amdgcn_global_load_lds(
      (__attribute__((address_space(1))) void*)g,
      (__attribute__((address_space(3))) void*)l, 16, 0, 0);
}

// ---------------- fp32 -> bf16 convert ----------------
__global__ __launch_bounds__(256) void k_cvt(const float* __restrict__ in,
                                             unsigned short* __restrict__ out, int n4) {
  int i = blockIdx.x * 256 + threadIdx.x;
  if (i >= n4) return;
  float4 v = ((const float4*)in)[i];
  ushort4 o;
  o.x = f2bf(v.x); o.y = f2bf(v.y); o.z = f2bf(v.z); o.w = f2bf(v.w);
  ((ushort4*)out)[i] = o;
}

// ---------------- GEMM 256x256, BK=64, 8-phase pipeline, deep counted vmcnt -
// Per K-tile: 4 phases {ds_read frags; stage 1 unit; barrier; lgkm0; 16 MFMA;
// [vmcnt(8) at P1/P3]; barrier}. Waits keep 8 loads in flight at all times;
// each guards exactly the half-tile read one phase later (FIFO-verified).
template <int OUT_BF16>
__global__ __launch_bounds__(512, 1) void k_gemm256(const unsigned short* __restrict__ A,
                                                    const unsigned short* __restrict__ Bt,
                                                    void* __restrict__ Cout,
                                                    int M, int N, int K) {
  __shared__ __align__(16) unsigned short As[2][2][256 * 32];
  __shared__ __align__(16) unsigned short Bs[2][2][256 * 32];
  const int t = threadIdx.x, lane = t & 63;
  const int wid = t >> 6, wm = wid >> 2, wn = wid & 3;
  const int fr = lane & 15, kq = lane >> 4;
  const int nwg = gridDim.x * gridDim.y;   // % 8 == 0 at both call sites
  int lin = blockIdx.y * gridDim.x + blockIdx.x;
  lin = (lin & 7) * (nwg >> 3) + (lin >> 3);
  const int bx = lin % gridDim.x, by = lin / gridDim.x;
  const int row0 = by * 256, col0 = bx * 256;
  const int NT = K >> 6;

  int srow[2], sgs[2];
#pragma unroll
  for (int i = 0; i < 2; ++i) {
    const int off = (i * 512 + t) * 16;
    srow[i] = off >> 6;
    sgs[i] = (((off >> 4) & 3) - (srow[i] >> 1)) & 3;
  }

#define STAGE_A(KT, KS)                                                        \
  do {                                                                         \
    const int b_ = (KT) & 1;                                                   \
    _Pragma("unroll") for (int i = 0; i < 2; ++i)                              \
        gload16(A + (size_t)(row0 + srow[i]) * K + (KT) * 64 + (KS) * 32 +     \
                    sgs[i] * 8,                                                \
                (char*)&As[b_][KS][0] + i * 8192 + wid * 1024);                \
  } while (0)
#define STAGE_B(KT, KS)                                                        \
  do {                                                                         \
    const int b_ = (KT) & 1;                                                   \
    _Pragma("unroll") for (int i = 0; i < 2; ++i)                              \
        gload16(Bt + (size_t)(col0 + srow[i]) * K + (KT) * 64 + (KS) * 32 +    \
                    sgs[i] * 8,                                                \
                (char*)&Bs[b_][KS][0] + i * 8192 + wid * 1024);                \
  } while (0)
#define LDFRAG(BUFP, ROW) \
  (*(const bf16x8*)((const char*)(BUFP) + (ROW) * 64 + ((((ROW) >> 1) + kq & 3) << 4)))

  f32x4 acc[8][4];
#pragma unroll
  for (int m = 0; m < 8; ++m)
#pragma unroll
    for (int n = 0; n < 4; ++n) acc[m][n] = f32x4{0.f, 0.f, 0.f, 0.f};

  // prologue: U(0,ks0), U(0,ks1), U(1,ks0); wait only for U(0,ks0)
  STAGE_A(0, 0); STAGE_B(0, 0); STAGE_A(0, 1); STAGE_B(0, 1);
  STAGE_A(1, 0); STAGE_B(1, 0);
  asm volatile("s_waitcnt vmcnt(8)" ::: "memory");
  __builtin_amdgcn_s_barrier();

  for (int kt = 0; kt < NT; ++kt) {
    const unsigned short* As0 = &As[kt & 1][0][0];
    const unsigned short* As1 = &As[kt & 1][1][0];
    const unsigned short* Bs0 = &Bs[kt & 1][0][0];
    const unsigned short* Bs1 = &Bs[kt & 1][1][0];
    bf16x8 a0[4], a1[4], b0[4], b1[4];

    // ---- phase 0: ks0/mh0 ----
#pragma unroll
    for (int m = 0; m < 4; ++m) a0[m] = LDFRAG(As0, wm * 128 + m * 16 + fr);
#pragma unroll
    for (int n = 0; n < 4; ++n) b0[n] = LDFRAG(Bs0, wn * 64 + n * 16 + fr);
    if (kt + 1 < NT) STAGE_A(kt + 1, 1);
    __builtin_amdgcn_sched_barrier(0);
    __builtin_amdgcn_s_barrier();
    asm volatile("s_waitcnt lgkmcnt(0)" ::: "memory");
    __builtin_amdgcn_sched_barrier(0);
    __builtin_amdgcn_s_setprio(1);
#pragma unroll
    for (int m = 0; m < 4; ++m)
#pragma unroll
      for (int n = 0; n < 4; ++n)
        acc[m][n] = __builtin_amdgcn_mfma_f32_16x16x32_bf16(a0[m], b0[n], acc[m][n], 0, 0, 0);
    __builtin_amdgcn_s_setprio(0);
    __builtin_amdgcn_s_barrier();

    // ---- phase 1: ks0/mh1 ; wait guards this tile's ks1 (read at P2) ----
#pragma unroll
    for (int m = 0; m < 4; ++m) a1[m] = LDFRAG(As0, wm * 128 + 64 + m * 16 + fr);
    if (kt + 1 < NT) STAGE_B(kt + 1, 1);
    __builtin_amdgcn_sched_barrier(0);
    __builtin_amdgcn_s_barrier();
    asm volatile("s_waitcnt lgkmcnt(0)" ::: "memory");
    __builtin_amdgcn_sched_barrier(0);
    __builtin_amdgcn_s_setprio(1);
#pragma unroll
    for (int m = 0; m < 4; ++m)
#pragma unroll
      for (int n = 0; n < 4; ++n)
        acc[m + 4][n] = __builtin_amdgcn_mfma_f32_16x16x32_bf16(a1[m], b0[n], acc[m + 4][n], 0, 0, 0);
    __builtin_amdgcn_s_setprio(0);
    if (kt + 1 < NT) asm volatile("s_waitcnt vmcnt(8)" ::: "memory");
    else             asm volatile("s_waitcnt vmcnt(0)" ::: "memory");
    __builtin_amdgcn_sched_barrier(0);
    __builtin_amdgcn_s_barrier();

    // ---- phase 2: ks1/mh0 ----
#pragma unroll
    for (int m = 0; m < 4; ++m) a0[m] = LDFRAG(As1, wm * 128 + m * 16 + fr);
#pragma unroll
    for (int n = 0; n < 4; ++n) b1[n] = LDFRAG(Bs1, wn * 64 + n * 16 + fr);
    if (kt + 2 < NT) STAGE_A(kt + 2, 0);
    __builtin_amdgcn_sched_barrier(0);
    __builtin_amdgcn_s_barrier();
    asm volatile("s_waitcnt lgkmcnt(0)" ::: "memory");
    __builtin_amdgcn_sched_barrier(0);
    __builtin_amdgcn_s_setprio(1);
#pragma unroll
    for (int m = 0; m < 4; ++m)
#pragma unroll
      for (int n = 0; n < 4; ++n)
        acc[m][n] = __builtin_amdgcn_mfma_f32_16x16x32_bf16(a0[m], b1[n], acc[m][n], 0, 0, 0);
    __builtin_amdgcn_s_setprio(0);
    __builtin_amdgcn_s_barrier();

    // ---- phase 3: ks1/mh1 ; wait guards next tile's ks0 (read at next P0) --
#pragma unroll
    for (int m = 0; m < 4; ++m) a1[m] = LDFRAG(As1, wm * 128 + 64 + m * 16 + fr);
    if (kt + 2 < NT) STAGE_B(kt + 2, 0);
    __builtin_amdgcn_sched_barrier(0);
    __builtin_amdgcn_s_barrier();
    asm volatile("s_waitcnt lgkmcnt(0)" ::: "memory");
    __builtin_amdgcn_sched_barrier(0);
    __builtin_amdgcn_s_setprio(1);
#pragma unroll
    for (int m = 0; m < 4; ++m)
#pragma unroll
      for (int n = 0; n < 4; ++n)
        acc[m + 4][n] = __builtin_amdgcn_mfma_f32_16x16x32_bf16(a1[m], b1[n], acc[m + 4][n], 0, 0, 0);
    __builtin_amdgcn_s_setprio(0);
    if (kt + 2 < NT)      asm volatile("s_waitcnt vmcnt(8)" ::: "memory");
    else if (kt + 1 < NT) asm volatile("s_waitcnt vmcnt(4)" ::: "memory");
    __builtin_amdgcn_sched_barrier(0);
    __builtin_amdgcn_s_barrier();
  }
#undef STAGE_A
#undef STAGE_B
#undef LDFRAG

  const int rsub = kq * 4;
#pragma unroll
  for (int m = 0; m < 8; ++m)
#pragma unroll
    for (int n = 0; n < 4; ++n)
#pragma unroll
      for (int r = 0; r < 4; ++r) {
        const size_t row = (size_t)row0 + wm * 128 + m * 16 + rsub + r;
        const size_t col = (size_t)col0 + wn * 64 + n * 16 + fr;
        if (OUT_BF16)
          ((unsigned short*)Cout)[row * N + col] = f2bf(acc[m][n][r]);
        else
          ((float*)Cout)[row * N + col] = acc[m][n][r];
      }
}

// ---------------- RoPE + head split (qkv bf16 -> Q/K bf16; V not launched) --
__global__ __launch_bounds__(256) void k_rope(const unsigned short* __restrict__ qkv,
                                              const float* __restrict__ fcos,
                                              const float* __restrict__ fsin,
                                              unsigned short* __restrict__ Qb,
                                              unsigned short* __restrict__ Kb) {
  const int idx = blockIdx.x * 256 + threadIdx.x;  // < 4096*640
  if (idx >= 4096 * 640) return;
  const int bt = idx / 640;
  const int r = idx - bt * 640;
  const int g = r / 80;
  const int rr = r - g * 80;
  const int slot = rr >> 4;            // 0..4
  const int d0 = (rr & 15) * 8;
  const int o0 = g * 768 + slot * 128 + d0;
  const int b = bt >> 10, tt = bt & 1023;

  uint4 raw = *(const uint4*)&qkv[(size_t)bt * 6144 + o0];
  unsigned short us[8] = {
      (unsigned short)(raw.x & 0xffff), (unsigned short)(raw.x >> 16),
      (unsigned short)(raw.y & 0xffff), (unsigned short)(raw.y >> 16),
      (unsigned short)(raw.z & 0xffff), (unsigned short)(raw.z >> 16),
      (unsigned short)(raw.w & 0xffff), (unsigned short)(raw.w >> 16)};

  float4 c = *(const float4*)&fcos[tt * 64 + (d0 >> 1)];
  float4 s = *(const float4*)&fsin[tt * 64 + (d0 >> 1)];
  const float sc = (slot < 4) ? 0.08838834764831845f : 1.0f;  // 1/sqrt(128) into Q
  float cj[4] = {c.x, c.y, c.z, c.w};
  float sj[4] = {s.x, s.y, s.z, s.w};
  unsigned short os[8];
#pragma unroll
  for (int j = 0; j < 4; ++j) {
    float x0 = bf2f(us[2 * j]), x1 = bf2f(us[2 * j + 1]);
    os[2 * j] = f2bf((x0 * cj[j] - x1 * sj[j]) * sc);
    os[2 * j + 1] = f2bf((x0 * sj[j] + x1 * cj[j]) * sc);
  }
  if (slot < 4) {
    const int h = g * 4 + slot;
    *(uint4*)&Qb[((size_t)(b * 32 + h) * 1024 + tt) * 128 + d0] = pack8(os);
  } else {
    *(uint4*)&Kb[((size_t)(b * 8 + g) * 1024 + tt) * 128 + d0] = pack8(os);
  }
}

// ---------------- V transpose: QKVB -> VT[bg][d=128][t=1024] ----------------
__global__ __launch_bounds__(256) void k_vtrans(const unsigned short* __restrict__ qkv,
                                                unsigned short* __restrict__ VT) {
  const int t = threadIdx.x;
  const int tt0 = blockIdx.x * 128;
  const int bg = blockIdx.y;
  const int b = bg >> 3, g = bg & 7;
  const int tj = t & 15;
  const int ti = t >> 4;
  union U4 { uint4 v; unsigned int u[4]; };
  U4 in[8], out[8];
  const unsigned short* src =
      qkv + (size_t)(b * 1024 + tt0 + ti * 8) * 6144 + g * 768 + 640 + tj * 8;
#pragma unroll
  for (int r = 0; r < 8; ++r) in[r].v = *(const uint4*)(src + (size_t)r * 6144);
#pragma unroll
  for (int c = 0; c < 8; ++c) {
    const unsigned int sel = (c & 1) ? 0x07060302u : 0x05040100u;
    const int dw = c >> 1;
#pragma unroll
    for (int w = 0; w < 4; ++w)
      out[c].u[w] = __builtin_amdgcn_perm(in[2 * w + 1].u[dw], in[2 * w].u[dw], sel);
  }
  unsigned short* dst = VT + (size_t)bg * 131072 + (size_t)(tj * 8) * 1024 + tt0 + ti * 8;
#pragma unroll
  for (int c = 0; c < 8; ++c) *(uint4*)(dst + (size_t)c * 1024) = out[c].v;
}

// ---------------- causal GQA flash attention: group-shared K/V staging ------
// block = (b,g) x 64-row q-tile; 512 thr = 8 waves = 4 heads x 2 row-halves.
// K/V staged ONCE per block, shared by all 4 heads (4x fewer stage events).
// dbuf + counted vmcnt(4); each iter closes with lgkm0+barrier so the next
// iter's stage (overwriting the buffer read 2 iters ago) is WAR-safe.
__global__ __launch_bounds__(512, 1) void k_attn(const unsigned short* __restrict__ Qb,
                                                 const unsigned short* __restrict__ Kb,
                                                 const unsigned short* __restrict__ VT,
                                                 unsigned short* __restrict__ AO) {
  __shared__ __align__(16) unsigned short Ks[2][64 * 128];  // [kv][d] 256B rows, XOR-swz
  __shared__ __align__(16) unsigned short Vt[2][128 * 64];  // [d][kv] 128B rows, XOR-swz
  __shared__ __align__(16) unsigned short Ps[8][32 * 64];   // per-wave [q32][kv64], XOR-swz
  const int t = threadIdx.x, lane = t & 63, wid = t >> 6;
  const int hh = wid >> 1, qh = wid & 1;      // head-in-group, row-half
  const int bg = blockIdx.x, b = bg >> 3, g = bg & 7;
  const int qi = 15 - (int)blockIdx.y;        // longest-first
  const int q0 = qi * 64;
  const int h = g * 4 + hh;
  const int fr = lane & 15, kq = lane >> 4;
  const size_t kvbase = (size_t)bg * (1024 * 128);
  const size_t vtbase = (size_t)bg * (128 * 1024);

  // 4 gload16/thread per stage -> vmcnt(4) waits for exactly the prior stage
#define ASTAGE(TILE, BUF)                                                      \
  do {                                                                         \
    const int kv0_ = (TILE) * 64;                                              \
    _Pragma("unroll") for (int it = 0; it < 2; ++it) {                         \
      const int off = it * 8192 + t * 16;                                      \
      const int r_ = off >> 8, cb_ = off & 255;                                \
      const int scb_ = cb_ ^ ((r_ & 7) << 4);                                  \
      gload16(Kb + kvbase + (size_t)(kv0_ + r_) * 128 + (scb_ >> 1),           \
              (char*)Ks[BUF] + off);                                           \
    }                                                                          \
    _Pragma("unroll") for (int it = 0; it < 2; ++it) {                         \
      const int off = it * 8192 + t * 16;                                      \
      const int rd_ = off >> 7, cb_ = off & 127;                               \
      const int scb_ = cb_ ^ ((rd_ & 7) << 4);                                 \
      gload16(VT + vtbase + (size_t)rd_ * 1024 + kv0_ + (scb_ >> 1),           \
              (char*)Vt[BUF] + off);                                           \
    }                                                                          \
  } while (0)

  bf16x8 qf[2][4];
  {
    const unsigned short* Qp0 = Qb + ((size_t)(b * 32 + h) * 1024 + q0 + qh * 32) * 128;
#pragma unroll
    for (int qr = 0; qr < 2; ++qr)
#pragma unroll
      for (int ks = 0; ks < 4; ++ks)
        qf[qr][ks] = *(const bf16x8*)&Qp0[(size_t)(qr * 16 + fr) * 128 + ks * 32 + kq * 8];
  }
  float mrow[2][4], lrow[2][4];
#pragma unroll
  for (int qr = 0; qr < 2; ++qr)
#pragma unroll
    for (int rg = 0; rg < 4; ++rg) { mrow[qr][rg] = -1e30f; lrow[qr][rg] = 0.f; }
  f32x4 of[2][8];
#pragma unroll
  for (int qr = 0; qr < 2; ++qr)
#pragma unroll
    for (int n = 0; n < 8; ++n) of[qr][n] = f32x4{0.f, 0.f, 0.f, 0.f};

  const int ntiles = qi + 1;
  ASTAGE(0, 0);

  for (int kt = 0; kt < ntiles; ++kt) {
    const int buf = kt & 1;
    const int kv0 = kt * 64;
    if (kt + 1 < ntiles) {
      ASTAGE(kt + 1, buf ^ 1);  // WAR-safe: buf^1 last read at iter kt-1, closed by lgkm0+barrier
      asm volatile("s_waitcnt vmcnt(4)" ::: "memory");
    } else {
      asm volatile("s_waitcnt vmcnt(0)" ::: "memory");
    }
    __builtin_amdgcn_s_barrier();  // stage(kt) landed for all waves
    __builtin_amdgcn_sched_barrier(0);

    // S = Q K^T : per wave 32q x 64kv
    f32x4 sacc[2][4];
#pragma unroll
    for (int qr = 0; qr < 2; ++qr)
#pragma unroll
      for (int n = 0; n < 4; ++n) sacc[qr][n] = f32x4{0.f, 0.f, 0.f, 0.f};
#pragma unroll
    for (int n = 0; n < 4; ++n) {
      const int row = n * 16 + fr;
      const int sw = (row & 7) << 4;
      bf16x8 kf[4];
#pragma unroll
      for (int ks = 0; ks < 4; ++ks)
        kf[ks] = *(const bf16x8*)((const char*)Ks[buf] + row * 256 + ((ks * 64 + kq * 16) ^ sw));
      __builtin_amdgcn_s_setprio(1);
#pragma unroll
      for (int qr = 0; qr < 2; ++qr)
#pragma unroll
        for (int ks = 0; ks < 4; ++ks)
          sacc[qr][n] =
              __builtin_amdgcn_mfma_f32_16x16x32_bf16(qf[qr][ks], kf[ks], sacc[qr][n], 0, 0, 0);
      __builtin_amdgcn_s_setprio(0);
    }

    // online softmax; rows q = qh*32 + qr*16 + kq*4 + rg, cols kv = n*16+fr
#pragma unroll
    for (int qr = 0; qr < 2; ++qr)
#pragma unroll
      for (int rg = 0; rg < 4; ++rg) {
        const int qrow = q0 + qh * 32 + qr * 16 + kq * 4 + rg;
        float s[4];
#pragma unroll
        for (int n = 0; n < 4; ++n) {
          s[n] = sacc[qr][n][rg];
          if (kv0 + n * 16 + fr > qrow) s[n] = -1e30f;
        }
        float mx = fmaxf(fmaxf(s[0], s[1]), fmaxf(s[2], s[3]));
#pragma unroll
        for (int o = 1; o < 16; o <<= 1) mx = fmaxf(mx, __shfl_xor(mx, o));
        const float mnew = fmaxf(mrow[qr][rg], mx);
        float p[4];
#pragma unroll
        for (int n = 0; n < 4; ++n) p[n] = __expf(s[n] - mnew);
        float sum = (p[0] + p[1]) + (p[2] + p[3]);
#pragma unroll
        for (int o = 1; o < 16; o <<= 1) sum += __shfl_xor(sum, o);
        const float fac = __expf(mrow[qr][rg] - mnew);
        lrow[qr][rg] = lrow[qr][rg] * fac + sum;
        mrow[qr][rg] = mnew;
#pragma unroll
        for (int n = 0; n < 8; ++n) of[qr][n][rg] *= fac;
        const int q = qr * 16 + kq * 4 + rg;
        const int swp = (q & 7) << 4;
#pragma unroll
        for (int n = 0; n < 4; ++n)
          *(unsigned short*)((char*)Ps[wid] + q * 128 + ((2 * (n * 16 + fr)) ^ swp)) =
              f2bf(p[n]);
      }
    asm volatile("s_waitcnt lgkmcnt(0)" ::: "memory");
    __builtin_amdgcn_sched_barrier(0);

    // PV: O += P[32x64] * V^T  (per-wave Ps)
    bf16x8 pa[2][2];
#pragma unroll
    for (int qr = 0; qr < 2; ++qr) {
      const int prow = qr * 16 + fr;
      const int swp = (prow & 7) << 4;
#pragma unroll
      for (int kk = 0; kk < 2; ++kk)
        pa[qr][kk] = *(const bf16x8*)((const char*)Ps[wid] + prow * 128 +
                                      ((kk * 64 + kq * 16) ^ swp));
    }
#pragma unroll
    for (int n = 0; n < 8; ++n) {
      const int row = n * 16 + fr;
      const int sw = (row & 7) << 4;
      bf16x8 vf[2];
#pragma unroll
      for (int kk = 0; kk < 2; ++kk)
        vf[kk] = *(const bf16x8*)((const char*)Vt[buf] + row * 128 + ((kk * 64 + kq * 16) ^ sw));
      __builtin_amdgcn_s_setprio(1);
#pragma unroll
      for (int qr = 0; qr < 2; ++qr)
#pragma unroll
        for (int kk = 0; kk < 2; ++kk)
          of[qr][n] = __builtin_amdgcn_mfma_f32_16x16x32_bf16(pa[qr][kk], vf[kk], of[qr][n], 0, 0, 0);
      __builtin_amdgcn_s_setprio(0);
    }
    asm volatile("s_waitcnt lgkmcnt(0)" ::: "memory");  // all buf reads drained
    __builtin_amdgcn_sched_barrier(0);
    __builtin_amdgcn_s_barrier();                       // release next iter's stage
  }
#undef ASTAGE

  float inv[2][4];
#pragma unroll
  for (int qr = 0; qr < 2; ++qr)
#pragma unroll
    for (int rg = 0; rg < 4; ++rg) inv[qr][rg] = 1.0f / lrow[qr][rg];
#pragma unroll
  for (int qr = 0; qr < 2; ++qr)
#pragma unroll
    for (int n = 0; n < 8; ++n)
#pragma unroll
      for (int rg = 0; rg < 4; ++rg) {
        const size_t row = (size_t)b * 1024 + q0 + qh * 32 + qr * 16 + kq * 4 + rg;
        const size_t col = (size_t)h * 128 + n * 16 + fr;
        AO[row * 4096 + col] = f2bf(of[qr][n][rg] * inv[qr][rg]);
      }
}

// ---------------- launch ----------------
extern "C" void kernel_launch(void* const* d_in, const int* in_sizes, int n_in,
                              void* d_out, int out_size, void* d_ws, size_t ws_size,
                              hipStream_t stream) {
  const float* x = (const float*)d_in[0];
  const float* w_qkv = (const float*)d_in[1];
  const float* w_proj = (const float*)d_in[2];
  const float* fcos = (const float*)d_in[3];
  const float* fsin = (const float*)d_in[4];
  float* out = (float*)d_out;

  char* ws = (char*)d_ws;
  unsigned short* XB    = (unsigned short*)(ws + 0);
  unsigned short* WQKVB = (unsigned short*)(ws + 33554432);
  unsigned short* QKVB  = (unsigned short*)(ws + 83886080);
  unsigned short* QB    = (unsigned short*)(ws + 134217728);
  unsigned short* KB    = (unsigned short*)(ws + 167772160);
  unsigned short* VTB   = (unsigned short*)(ws + 176160768);
  unsigned short* WPROJB = XB;
  unsigned short* AOB    = QKVB;

  k_cvt<<<16384, 256, 0, stream>>>(x, XB, 4194304);
  k_cvt<<<24576, 256, 0, stream>>>(w_qkv, WQKVB, 6291456);
  k_gemm256<1><<<dim3(24, 16), 512, 0, stream>>>(XB, WQKVB, QKVB, 4096, 6144, 4096);
  k_cvt<<<16384, 256, 0, stream>>>(w_proj, WPROJB, 4194304);
  k_rope<<<10240, 256, 0, stream>>>(QKVB, fcos, fsin, QB, KB);
  k_vtrans<<<dim3(8, 32), 256, 0, stream>>>(QKVB, VTB);
  k_attn<<<dim3(32, 16), 512, 0, stream>>>(QB, KB, VTB, AOB);
  k_gemm256<0><<<dim3(16, 16), 512, 0, stream>>>(AOB, WPROJB, out, 4096, 4096, 4096);
}